// Round 1
// baseline (274.306 us; speedup 1.0000x reference)
//
#include <hip/hip_runtime.h>

#define N_NODES 20000
#define N_EDGES 150000
#define FEAT 64
#define HEADS 8
#define N_RBF 20
#define COLS 1024   // 2 * HEADS * FEAT  (Q block then K block)

__device__ __forceinline__ unsigned short f2bf(float x) {
    unsigned int u = __float_as_uint(x);
    unsigned int r = (u + 0x7FFFu + ((u >> 16) & 1u)) >> 16;
    return (unsigned short)r;
}
__device__ __forceinline__ float bf2f(unsigned short b) {
    return __uint_as_float(((unsigned int)b) << 16);
}
__device__ __forceinline__ float silu(float x) {
    return x / (1.0f + __expf(-x));
}

// ---------------------------------------------------------------------------
// K1: per-node Q/K projection.  QK[n][c], c = qk*512 + h*64 + g  (bf16)
// grid = (16 col-tiles, ceil(20000/64) node-tiles), block = 256
// ---------------------------------------------------------------------------
__global__ __launch_bounds__(256) void qk_project(
    const float* __restrict__ x,    // [N_NODES][64]
    const float* __restrict__ Wq,   // [8][64][64]  (h,g,f) f contiguous
    const float* __restrict__ bq,   // [8][64]
    const float* __restrict__ Wk,
    const float* __restrict__ bk,
    unsigned short* __restrict__ qk) // [N_NODES][1024] bf16
{
    __shared__ float xs[64][65];    // [node][f], +1 pad
    __shared__ float wsb[64][65];   // [colLocal][f], +1 pad

    const int tid = threadIdx.x;
    const int colBase = blockIdx.x * 64;
    const int nodeBase = blockIdx.y * 64;
    const int f = tid & 63;

    for (int n = tid >> 6; n < 64; n += 4) {
        int node = nodeBase + n;
        xs[n][f] = (node < N_NODES) ? x[node * 64 + f] : 0.0f;
    }
    for (int cl = tid >> 6; cl < 64; cl += 4) {
        int c = colBase + cl;
        int hg = c & 511;
        const float* W = (c >> 9) ? Wk : Wq;
        wsb[cl][f] = W[hg * 64 + f];
    }
    __syncthreads();

    const int nb = (tid >> 4) * 4;   // 0..60
    const int cb = (tid & 15) * 4;   // 0..60

    float acc[4][4] = {};
#pragma unroll 8
    for (int k = 0; k < 64; ++k) {
        float a0 = xs[nb + 0][k], a1 = xs[nb + 1][k];
        float a2 = xs[nb + 2][k], a3 = xs[nb + 3][k];
        float b0 = wsb[cb + 0][k], b1 = wsb[cb + 1][k];
        float b2 = wsb[cb + 2][k], b3 = wsb[cb + 3][k];
        acc[0][0] += a0 * b0; acc[0][1] += a0 * b1; acc[0][2] += a0 * b2; acc[0][3] += a0 * b3;
        acc[1][0] += a1 * b0; acc[1][1] += a1 * b1; acc[1][2] += a1 * b2; acc[1][3] += a1 * b3;
        acc[2][0] += a2 * b0; acc[2][1] += a2 * b1; acc[2][2] += a2 * b2; acc[2][3] += a2 * b3;
        acc[3][0] += a3 * b0; acc[3][1] += a3 * b1; acc[3][2] += a3 * b2; acc[3][3] += a3 * b3;
    }

#pragma unroll
    for (int i = 0; i < 4; ++i) {
        int node = nodeBase + nb + i;
        if (node >= N_NODES) continue;
        int c0 = colBase + cb;
        ushort4 sv;
        {
            int hg = (c0 + 0) & 511; float bias = ((c0 + 0) >> 9) ? bk[hg] : bq[hg];
            sv.x = f2bf(acc[i][0] + bias);
        }
        {
            int hg = (c0 + 1) & 511; float bias = ((c0 + 1) >> 9) ? bk[hg] : bq[hg];
            sv.y = f2bf(acc[i][1] + bias);
        }
        {
            int hg = (c0 + 2) & 511; float bias = ((c0 + 2) >> 9) ? bk[hg] : bq[hg];
            sv.z = f2bf(acc[i][2] + bias);
        }
        {
            int hg = (c0 + 3) & 511; float bias = ((c0 + 3) >> 9) ? bk[hg] : bq[hg];
            sv.w = f2bf(acc[i][3] + bias);
        }
        *reinterpret_cast<ushort4*>(&qk[(size_t)node * COLS + c0]) = sv;
    }
}

// ---------------------------------------------------------------------------
// K2: fused edge kernel.  One wave per edge; lane = g.
// LDS: W_dk [h][f][20] f32 (40KB, base 80B-aligned per (h,f) -> float4 reads)
// ---------------------------------------------------------------------------
__global__ __launch_bounds__(256) void edge_attn(
    const float* __restrict__ dist,
    const int* __restrict__ nbrs,      // [E][2]
    const float* __restrict__ Wdk,     // [8][64][20]
    const float* __restrict__ bdk,     // [8][64]
    const unsigned short* __restrict__ qk, // [N][1024] bf16
    float* __restrict__ out)           // [E][8]
{
    __shared__ float wdk_s[HEADS * FEAT * N_RBF]; // 10240 f32
    __shared__ float bdk_s[HEADS * FEAT];

    const int tid = threadIdx.x;
    for (int i = tid; i < HEADS * FEAT * N_RBF; i += 256) wdk_s[i] = Wdk[i];
    for (int i = tid; i < HEADS * FEAT; i += 256) bdk_s[i] = bdk[i];
    __syncthreads();

    const int lane = tid & 63;
    const int waveId = blockIdx.x * 4 + (tid >> 6);
    const int nWaves = gridDim.x * 4;

    for (int e = waveId; e < N_EDGES; e += nWaves) {
        float d = dist[e];
        int ni = nbrs[2 * e + 0];
        int nj = nbrs[2 * e + 1];

        float theta = 0.62831853071795864769f * d;   // pi*d/5
        float s1, c1;
        __sincosf(theta, &s1, &c1);
        float env = (d < 5.0f) ? 0.5f * (c1 + 1.0f) : 0.0f;
        float scale = env / d;

        // ef[r] = sin((r+1)*theta) * scale via Chebyshev recurrence
        float ef[N_RBF];
        {
            float twoc = 2.0f * c1;
            float sm1 = 0.0f, s = s1;
#pragma unroll
            for (int r = 0; r < N_RBF; ++r) {
                ef[r] = s * scale;
                float nx = twoc * s - sm1;
                sm1 = s; s = nx;
            }
        }

        const unsigned short* qrow = qk + (size_t)ni * COLS + lane;         // Q block
        const unsigned short* krow = qk + (size_t)nj * COLS + 512 + lane;   // K block

        float hsum[HEADS];
#pragma unroll
        for (int h = 0; h < HEADS; ++h) {
            float qv = bf2f(qrow[h * 64]);
            float kv = bf2f(krow[h * 64]);
            const float* wrow = &wdk_s[(h * 64 + lane) * N_RBF];
            float pre = bdk_s[h * 64 + lane];
#pragma unroll
            for (int r4 = 0; r4 < 5; ++r4) {
                float4 w = *reinterpret_cast<const float4*>(wrow + 4 * r4);
                pre += ef[4 * r4 + 0] * w.x + ef[4 * r4 + 1] * w.y
                     + ef[4 * r4 + 2] * w.z + ef[4 * r4 + 3] * w.w;
            }
            float dk = silu(pre);
            hsum[h] = qv * kv * dk;
        }

        // full 64-lane butterfly reduce for each head
#pragma unroll
        for (int h = 0; h < HEADS; ++h) {
            float v = hsum[h];
            v += __shfl_xor(v, 32, 64);
            v += __shfl_xor(v, 16, 64);
            v += __shfl_xor(v, 8, 64);
            v += __shfl_xor(v, 4, 64);
            v += __shfl_xor(v, 2, 64);
            v += __shfl_xor(v, 1, 64);
            hsum[h] = v;
        }

        float w = hsum[0];
#pragma unroll
        for (int h = 1; h < HEADS; ++h)
            if (lane == h) w = hsum[h];
        if (lane < HEADS)
            out[(size_t)e * HEADS + lane] = silu(w);
    }
}

extern "C" void kernel_launch(void* const* d_in, const int* in_sizes, int n_in,
                              void* d_out, int out_size, void* d_ws, size_t ws_size,
                              hipStream_t stream) {
    const float* dist = (const float*)d_in[0];
    const int* nbrs   = (const int*)d_in[1];
    const float* x_i  = (const float*)d_in[2];
    const float* W_q  = (const float*)d_in[3];
    const float* b_q  = (const float*)d_in[4];
    const float* W_k  = (const float*)d_in[5];
    const float* b_k  = (const float*)d_in[6];
    const float* W_dk = (const float*)d_in[7];
    const float* b_dk = (const float*)d_in[8];
    float* out = (float*)d_out;

    unsigned short* qkbuf = (unsigned short*)d_ws;  // 20000*1024 bf16 = 41 MB

    dim3 g1(COLS / 64, (N_NODES + 63) / 64);
    qk_project<<<g1, 256, 0, stream>>>(x_i, W_q, b_q, W_k, b_k, qkbuf);

    edge_attn<<<768, 256, 0, stream>>>(dist, nbrs, W_dk, b_dk, qkbuf, out);
}

// Round 3
// 258.530 us; speedup vs baseline: 1.0610x; 1.0610x over previous
//
#include <hip/hip_runtime.h>

#define N_NODES 20000
#define N_EDGES 150000
#define FEAT 64
#define HEADS 8
#define N_RBF 20
#define COLS 1024   // 2 * HEADS * FEAT  (Q block then K block)

__device__ __forceinline__ unsigned short f2bf(float x) {
    unsigned int u = __float_as_uint(x);
    unsigned int r = (u + 0x7FFFu + ((u >> 16) & 1u)) >> 16;
    return (unsigned short)r;
}
__device__ __forceinline__ float silu(float x) {
    return x / (1.0f + __expf(-x));
}
// v += dpp(v, ctrl); masked-off rows receive 0 (bound_ctrl=true) and
// rows outside row_mask keep v (add identity handled by old=0 operand).
template <int CTRL, int ROW_MASK>
__device__ __forceinline__ float dpp_add(float v) {
    int t = __builtin_amdgcn_update_dpp(0, __float_as_int(v), CTRL, ROW_MASK, 0xF, true);
    return v + __int_as_float(t);
}

// ---------------------------------------------------------------------------
// K1: per-node Q/K projection.  QK[n][c], c = qk*512 + h*64 + g  (bf16)
// ---------------------------------------------------------------------------
__global__ __launch_bounds__(256) void qk_project(
    const float* __restrict__ x,
    const float* __restrict__ Wq,
    const float* __restrict__ bq,
    const float* __restrict__ Wk,
    const float* __restrict__ bk,
    unsigned short* __restrict__ qk)
{
    __shared__ float xs[64][65];
    __shared__ float wsb[64][65];

    const int tid = threadIdx.x;
    const int colBase = blockIdx.x * 64;
    const int nodeBase = blockIdx.y * 64;
    const int f = tid & 63;

    for (int n = tid >> 6; n < 64; n += 4) {
        int node = nodeBase + n;
        xs[n][f] = (node < N_NODES) ? x[node * 64 + f] : 0.0f;
    }
    for (int cl = tid >> 6; cl < 64; cl += 4) {
        int c = colBase + cl;
        int hg = c & 511;
        const float* W = (c >> 9) ? Wk : Wq;
        wsb[cl][f] = W[hg * 64 + f];
    }
    __syncthreads();

    const int nb = (tid >> 4) * 4;
    const int cb = (tid & 15) * 4;

    float acc[4][4] = {};
#pragma unroll 8
    for (int k = 0; k < 64; ++k) {
        float a0 = xs[nb + 0][k], a1 = xs[nb + 1][k];
        float a2 = xs[nb + 2][k], a3 = xs[nb + 3][k];
        float b0 = wsb[cb + 0][k], b1 = wsb[cb + 1][k];
        float b2 = wsb[cb + 2][k], b3 = wsb[cb + 3][k];
        acc[0][0] += a0 * b0; acc[0][1] += a0 * b1; acc[0][2] += a0 * b2; acc[0][3] += a0 * b3;
        acc[1][0] += a1 * b0; acc[1][1] += a1 * b1; acc[1][2] += a1 * b2; acc[1][3] += a1 * b3;
        acc[2][0] += a2 * b0; acc[2][1] += a2 * b1; acc[2][2] += a2 * b2; acc[2][3] += a2 * b3;
        acc[3][0] += a3 * b0; acc[3][1] += a3 * b1; acc[3][2] += a3 * b2; acc[3][3] += a3 * b3;
    }

#pragma unroll
    for (int i = 0; i < 4; ++i) {
        int node = nodeBase + nb + i;
        if (node >= N_NODES) continue;
        int c0 = colBase + cb;
        ushort4 sv;
        { int hg = (c0+0)&511; float bias = ((c0+0)>>9) ? bk[hg] : bq[hg]; sv.x = f2bf(acc[i][0]+bias); }
        { int hg = (c0+1)&511; float bias = ((c0+1)>>9) ? bk[hg] : bq[hg]; sv.y = f2bf(acc[i][1]+bias); }
        { int hg = (c0+2)&511; float bias = ((c0+2)>>9) ? bk[hg] : bq[hg]; sv.z = f2bf(acc[i][2]+bias); }
        { int hg = (c0+3)&511; float bias = ((c0+3)>>9) ? bk[hg] : bq[hg]; sv.w = f2bf(acc[i][3]+bias); }
        *reinterpret_cast<ushort4*>(&qk[(size_t)node * COLS + c0]) = sv;
    }
}

// ---------------------------------------------------------------------------
// K2: register-resident edge kernel.  wave <-> head-pair, zero LDS.
// lane: h = hp*2 + (lane>>5), g in {2*(lane&31), 2*(lane&31)+1}
// Per 64-edge batch: phase1 lane=edge computes ef[20]; phase2 loops edges,
// ef broadcast via v_readlane (SGPR operand to v_fmac), W_dk in 40 VGPRs.
// Reduce: 5 DPP adds (ror8, ror4, qpxor2, qpxor1, row_bcast15).
// ---------------------------------------------------------------------------
__global__ __launch_bounds__(256) void edge_attn(
    const float* __restrict__ dist,
    const int* __restrict__ nbrs,      // [E][2]
    const float* __restrict__ Wdk,     // [8][64][20]
    const float* __restrict__ bdk,     // [8][64]
    const unsigned short* __restrict__ qk, // [N][1024] bf16
    float* __restrict__ out)           // [E][8]
{
    const int lane = threadIdx.x & 63;
    const int wid = blockIdx.x * 4 + (threadIdx.x >> 6);
    const int hp = wid & 3;                 // head pair 0..3
    const int h  = hp * 2 + (lane >> 5);    // this lane's head
    const int g0 = (lane & 31) * 2;

    // W_dk rows for (h, g0) and (h, g0+1): 40 VGPRs, loaded once
    float w0[N_RBF], w1[N_RBF];
    const float* wr = Wdk + (h * 64 + g0) * N_RBF;
#pragma unroll
    for (int r = 0; r < N_RBF; ++r) { w0[r] = wr[r]; w1[r] = wr[N_RBF + r]; }
    const float b0 = bdk[h * 64 + g0];
    const float b1 = bdk[h * 64 + g0 + 1];

    const int qoff = (h * 64 + g0) * 2;     // byte offset of this lane's 2 cols

    const int NB = (N_EDGES + 63) / 64;
    const int nChunks = (gridDim.x * 4) >> 2;

    for (int eb = wid >> 2; eb < NB; eb += nChunks) {
        const int e0 = eb * 64;
        const int e = e0 + lane;
        const bool val = e < N_EDGES;

        float d = 1.0f;
        int vni = 0, vnj = 0;
        if (val) {
            d = dist[e];
            int2 nn = *reinterpret_cast<const int2*>(&nbrs[2 * e]);
            vni = nn.x; vnj = nn.y;
        }

        float theta = 0.62831853071795864769f * d;   // pi*d/5
        float s1, c1;
        __sincosf(theta, &s1, &c1);
        float env = (d < 5.0f) ? 0.5f * (c1 + 1.0f) : 0.0f;
        float scale = env / d;

        float ef[N_RBF];
        {
            float twoc = 2.0f * c1, sm1 = 0.0f, ss = s1;
#pragma unroll
            for (int r = 0; r < N_RBF; ++r) {
                ef[r] = ss * scale;
                float nx = twoc * ss - sm1;
                sm1 = ss; ss = nx;
            }
        }

        const int cnt = min(64, N_EDGES - e0);
        for (int e2 = 0; e2 < cnt; ++e2) {
            const int ni = __builtin_amdgcn_readlane(vni, e2);
            const int nj = __builtin_amdgcn_readlane(vnj, e2);
            const unsigned int qd = *reinterpret_cast<const unsigned int*>(
                reinterpret_cast<const char*>(qk) + (size_t)ni * 2048 + qoff);
            const unsigned int kd = *reinterpret_cast<const unsigned int*>(
                reinterpret_cast<const char*>(qk) + (size_t)nj * 2048 + 1024 + qoff);

            float pre0 = b0, pre1 = b1;
#pragma unroll
            for (int r = 0; r < N_RBF; ++r) {
                float efr = __int_as_float(
                    __builtin_amdgcn_readlane(__float_as_int(ef[r]), e2));
                pre0 = fmaf(efr, w0[r], pre0);
                pre1 = fmaf(efr, w1[r], pre1);
            }
            float dk0 = silu(pre0);
            float dk1 = silu(pre1);

            float q0 = __int_as_float(qd << 16);
            float q1 = __int_as_float(qd & 0xFFFF0000u);
            float k0 = __int_as_float(kd << 16);
            float k1 = __int_as_float(kd & 0xFFFF0000u);

            float t = fmaf(q1 * k1, dk1, q0 * k0 * dk0);

            // 32-lane half-reduce: row(16)-sums then cross-row via bcast15
            t = dpp_add<0x128, 0xF>(t);  // row_ror:8
            t = dpp_add<0x124, 0xF>(t);  // row_ror:4
            t = dpp_add<0x4E,  0xF>(t);  // quad_perm xor2
            t = dpp_add<0xB1,  0xF>(t);  // quad_perm xor1
            t = dpp_add<0x142, 0xA>(t);  // row_bcast15 into rows 1,3
            // lane 16 holds head hp*2 total, lane 48 holds head hp*2+1 total

            float wgt = silu(t);
            if ((lane & 31) == 16) {
                out[(size_t)(e0 + e2) * HEADS + h] = wgt;
            }
        }
    }
}

extern "C" void kernel_launch(void* const* d_in, const int* in_sizes, int n_in,
                              void* d_out, int out_size, void* d_ws, size_t ws_size,
                              hipStream_t stream) {
    const float* dist = (const float*)d_in[0];
    const int* nbrs   = (const int*)d_in[1];
    const float* x_i  = (const float*)d_in[2];
    const float* W_q  = (const float*)d_in[3];
    const float* b_q  = (const float*)d_in[4];
    const float* W_k  = (const float*)d_in[5];
    const float* b_k  = (const float*)d_in[6];
    const float* W_dk = (const float*)d_in[7];
    const float* b_dk = (const float*)d_in[8];
    float* out = (float*)d_out;

    unsigned short* qkbuf = (unsigned short*)d_ws;  // 20000*1024 bf16 = 41 MB

    dim3 g1(COLS / 64, (N_NODES + 63) / 64);
    qk_project<<<g1, 256, 0, stream>>>(x_i, W_q, b_q, W_k, b_k, qkbuf);

    edge_attn<<<1024, 256, 0, stream>>>(dist, nbrs, W_dk, b_dk, qkbuf, out);
}

// Round 6
// 157.791 us; speedup vs baseline: 1.7384x; 1.6384x over previous
//
#include <hip/hip_runtime.h>

#define N_NODES 20000
#define N_EDGES 150000
#define FEAT 64
#define HEADS 8
#define N_RBF 20
#define COLS 1024   // 2 * HEADS * FEAT  (Q block then K block)

__device__ __forceinline__ unsigned short f2bf(float x) {
    unsigned int u = __float_as_uint(x);
    unsigned int r = (u + 0x7FFFu + ((u >> 16) & 1u)) >> 16;
    return (unsigned short)r;
}
__device__ __forceinline__ float fsilu(float x) {
    // x / (1+e^-x) with hw rcp (~1e-7 rel err, fine vs 0.665 abs threshold)
    return x * __builtin_amdgcn_rcpf(1.0f + __expf(-x));
}
template <int CTRL, int ROW_MASK>
__device__ __forceinline__ float dpp_add(float v) {
    int t = __builtin_amdgcn_update_dpp(0, __float_as_int(v), CTRL, ROW_MASK, 0xF, true);
    return v + __int_as_float(t);
}

// ---------------------------------------------------------------------------
// K1: per-node Q/K projection.  QK[n][c], c = qk*512 + h*64 + g  (bf16)
// ---------------------------------------------------------------------------
__global__ __launch_bounds__(256) void qk_project(
    const float* __restrict__ x,
    const float* __restrict__ Wq,
    const float* __restrict__ bq,
    const float* __restrict__ Wk,
    const float* __restrict__ bk,
    unsigned short* __restrict__ qk)
{
    __shared__ float xs[64][65];
    __shared__ float wsb[64][65];

    const int tid = threadIdx.x;
    const int colBase = blockIdx.x * 64;
    const int nodeBase = blockIdx.y * 64;
    const int f = tid & 63;

    for (int n = tid >> 6; n < 64; n += 4) {
        int node = nodeBase + n;
        xs[n][f] = (node < N_NODES) ? x[node * 64 + f] : 0.0f;
    }
    for (int cl = tid >> 6; cl < 64; cl += 4) {
        int c = colBase + cl;
        int hg = c & 511;
        const float* W = (c >> 9) ? Wk : Wq;
        wsb[cl][f] = W[hg * 64 + f];
    }
    __syncthreads();

    const int nb = (tid >> 4) * 4;
    const int cb = (tid & 15) * 4;

    float acc[4][4] = {};
#pragma unroll 8
    for (int k = 0; k < 64; ++k) {
        float a0 = xs[nb + 0][k], a1 = xs[nb + 1][k];
        float a2 = xs[nb + 2][k], a3 = xs[nb + 3][k];
        float b0 = wsb[cb + 0][k], b1 = wsb[cb + 1][k];
        float b2 = wsb[cb + 2][k], b3 = wsb[cb + 3][k];
        acc[0][0] += a0 * b0; acc[0][1] += a0 * b1; acc[0][2] += a0 * b2; acc[0][3] += a0 * b3;
        acc[1][0] += a1 * b0; acc[1][1] += a1 * b1; acc[1][2] += a1 * b2; acc[1][3] += a1 * b3;
        acc[2][0] += a2 * b0; acc[2][1] += a2 * b1; acc[2][2] += a2 * b2; acc[2][3] += a2 * b3;
        acc[3][0] += a3 * b0; acc[3][1] += a3 * b1; acc[3][2] += a3 * b2; acc[3][3] += a3 * b3;
    }

#pragma unroll
    for (int i = 0; i < 4; ++i) {
        int node = nodeBase + nb + i;
        if (node >= N_NODES) continue;
        int c0 = colBase + cb;
        ushort4 sv;
        { int hg = (c0+0)&511; float bias = ((c0+0)>>9) ? bk[hg] : bq[hg]; sv.x = f2bf(acc[i][0]+bias); }
        { int hg = (c0+1)&511; float bias = ((c0+1)>>9) ? bk[hg] : bq[hg]; sv.y = f2bf(acc[i][1]+bias); }
        { int hg = (c0+2)&511; float bias = ((c0+2)>>9) ? bk[hg] : bq[hg]; sv.z = f2bf(acc[i][2]+bias); }
        { int hg = (c0+3)&511; float bias = ((c0+3)>>9) ? bk[hg] : bq[hg]; sv.w = f2bf(acc[i][3]+bias); }
        *reinterpret_cast<ushort4*>(&qk[(size_t)node * COLS + c0]) = sv;
    }
}

// ---------------------------------------------------------------------------
// K2: one block <-> one 64-edge batch; wave = head pair; W_dk pinned in VGPRs.
// ef broadcast via LDS uniform-address ds_read_b128 (5/iter, not 20 readlane).
// Per-iter results staged in per-wave LDS (lanes 16/48 ds_write_b32, same-wave
// readback needs no barrier); one coalesced float2 store per lane at the end.
// ---------------------------------------------------------------------------
__global__ __launch_bounds__(256, 4) void edge_attn(
    const float* __restrict__ dist,
    const int* __restrict__ nbrs,      // [E][2]
    const float* __restrict__ Wdk,     // [8][64][20]
    const float* __restrict__ bdk,     // [8][64]
    const unsigned short* __restrict__ qk, // [N][1024] bf16
    float* __restrict__ out)           // [E][8]
{
    __shared__ float4 ef_s[64 * 5];    // ef[e2][20] as 5 float4  (5 KB)
    __shared__ float  out_s[4][64][2]; // per-wave staging        (2 KB)

    const int tid = threadIdx.x;
    const int lane = tid & 63;
    const int wv = tid >> 6;           // head pair 0..3
    const int h0 = wv * 2;
    const int h  = h0 + (lane >> 5);   // this lane's head
    const int g0 = (lane & 31) * 2;

    const int e0 = blockIdx.x * 64;
    const int e = e0 + lane;
    const bool val = e < N_EDGES;

    // W_dk rows for (h,g0),(h,g0+1): 40 VGPRs, loaded once and pinned
    float w0[N_RBF], w1[N_RBF];
    {
        const float* wr = Wdk + (h * 64 + g0) * N_RBF;
#pragma unroll
        for (int r = 0; r < N_RBF; ++r) { w0[r] = wr[r]; w1[r] = wr[N_RBF + r]; }
#pragma unroll
        for (int r = 0; r < N_RBF; ++r) { asm volatile("" : "+v"(w0[r]), "+v"(w1[r])); }
    }
    const float b0 = bdk[h * 64 + g0];
    const float b1 = bdk[h * 64 + g0 + 1];

    // per-wave copies of neighbor indices (readlane source)
    int vni = 0, vnj = 0;
    if (val) {
        int2 nn = *reinterpret_cast<const int2*>(&nbrs[2 * e]);
        vni = nn.x; vnj = nn.y;
    }

    // wave 0 computes ef and stashes to LDS
    if (tid < 64) {
        float d = val ? dist[e] : 1.0f;
        float theta = 0.62831853071795864769f * d;   // pi*d/5
        float s1, c1;
        __sincosf(theta, &s1, &c1);
        float env = (d < 5.0f) ? 0.5f * (c1 + 1.0f) : 0.0f;
        float scale = env / d;
        float ef[N_RBF];
        float twoc = 2.0f * c1, sm1 = 0.0f, ss = s1;
#pragma unroll
        for (int r = 0; r < N_RBF; ++r) {
            ef[r] = ss * scale;
            float nx = twoc * ss - sm1;
            sm1 = ss; ss = nx;
        }
#pragma unroll
        for (int k = 0; k < 5; ++k)
            ef_s[lane * 5 + k] = make_float4(ef[4*k], ef[4*k+1], ef[4*k+2], ef[4*k+3]);
    }
    __syncthreads();

    const int qoff = (h * 64 + g0) * 2;   // byte offset of this lane's 2 cols
    const char* qkb = reinterpret_cast<const char*>(qk);
    const int cnt = min(64, N_EDGES - e0);

    for (int e2 = 0; e2 < cnt; ++e2) {
        const int ni = __builtin_amdgcn_readlane(vni, e2);
        const int nj = __builtin_amdgcn_readlane(vnj, e2);
        const unsigned int qd = *reinterpret_cast<const unsigned int*>(
            qkb + (size_t)ni * 2048 + qoff);
        const unsigned int kd = *reinterpret_cast<const unsigned int*>(
            qkb + (size_t)nj * 2048 + 1024 + qoff);

        // broadcast ef[e2][*]: 5 uniform-address ds_read_b128
        float efr[N_RBF];
        {
            float4 c0 = ef_s[e2 * 5 + 0];
            float4 c1 = ef_s[e2 * 5 + 1];
            float4 c2 = ef_s[e2 * 5 + 2];
            float4 c3 = ef_s[e2 * 5 + 3];
            float4 c4 = ef_s[e2 * 5 + 4];
            *reinterpret_cast<float4*>(&efr[0])  = c0;
            *reinterpret_cast<float4*>(&efr[4])  = c1;
            *reinterpret_cast<float4*>(&efr[8])  = c2;
            *reinterpret_cast<float4*>(&efr[12]) = c3;
            *reinterpret_cast<float4*>(&efr[16]) = c4;
        }

        float pre0 = b0, pre1 = b1;
#pragma unroll
        for (int r = 0; r < N_RBF; ++r) {
            pre0 = fmaf(efr[r], w0[r], pre0);
            pre1 = fmaf(efr[r], w1[r], pre1);
        }
        float dk0 = fsilu(pre0);
        float dk1 = fsilu(pre1);

        float q0 = __int_as_float(qd << 16);
        float q1 = __int_as_float(qd & 0xFFFF0000u);
        float k0 = __int_as_float(kd << 16);
        float k1 = __int_as_float(kd & 0xFFFF0000u);

        float t = fmaf(q1 * k1, dk1, q0 * k0 * dk0);

        // 32-lane reduce (per head half)
        t = dpp_add<0x128, 0xF>(t);  // row_ror:8
        t = dpp_add<0x124, 0xF>(t);  // row_ror:4
        t = dpp_add<0x4E,  0xF>(t);  // quad_perm xor2
        t = dpp_add<0xB1,  0xF>(t);  // quad_perm xor1
        t = dpp_add<0x142, 0xA>(t);  // row_bcast15 into rows 1,3

        // lanes 16 / 48 hold head h0 / h0+1 totals -> stage to per-wave LDS
        if ((lane & 31) == 16)
            out_s[wv][e2][lane >> 5] = fsilu(t);
    }

    // same-wave LDS visibility: waitcnt only (compiler emits), no barrier
    __builtin_amdgcn_s_waitcnt(0);  // lgkmcnt(0)&vmcnt(0)

    if (lane < cnt) {
        float2 o = *reinterpret_cast<const float2*>(&out_s[wv][lane][0]);
        *reinterpret_cast<float2*>(&out[(size_t)(e0 + lane) * HEADS + h0]) = o;
    }
}

extern "C" void kernel_launch(void* const* d_in, const int* in_sizes, int n_in,
                              void* d_out, int out_size, void* d_ws, size_t ws_size,
                              hipStream_t stream) {
    const float* dist = (const float*)d_in[0];
    const int* nbrs   = (const int*)d_in[1];
    const float* x_i  = (const float*)d_in[2];
    const float* W_q  = (const float*)d_in[3];
    const float* b_q  = (const float*)d_in[4];
    const float* W_k  = (const float*)d_in[5];
    const float* b_k  = (const float*)d_in[6];
    const float* W_dk = (const float*)d_in[7];
    const float* b_dk = (const float*)d_in[8];
    float* out = (float*)d_out;

    unsigned short* qkbuf = (unsigned short*)d_ws;  // 20000*1024 bf16 = 41 MB

    dim3 g1(COLS / 64, (N_NODES + 63) / 64);
    qk_project<<<g1, 256, 0, stream>>>(x_i, W_q, b_q, W_k, b_k, qkbuf);

    const int nb = (N_EDGES + 63) / 64;   // 2344 blocks, one batch each
    edge_attn<<<nb, 256, 0, stream>>>(dist, nbrs, W_dk, b_dk, qkbuf, out);
}

// Round 7
// 153.051 us; speedup vs baseline: 1.7923x; 1.0310x over previous
//
#include <hip/hip_runtime.h>

#define N_NODES 20000
#define N_EDGES 150000
#define FEAT 64
#define HEADS 8
#define N_RBF 20
#define COLS 1024   // 2 * HEADS * FEAT  (Q block then K block)

typedef __attribute__((ext_vector_type(8))) short short8;
typedef __attribute__((ext_vector_type(4))) float f32x4;

union frag_u { int4 i; short8 s; };

__device__ __forceinline__ unsigned short f2bf(float x) {
    unsigned int u = __float_as_uint(x);
    unsigned int r = (u + 0x7FFFu + ((u >> 16) & 1u)) >> 16;
    return (unsigned short)r;
}
__device__ __forceinline__ float fsilu(float x) {
    return x * __builtin_amdgcn_rcpf(1.0f + __expf(-x));
}

// ---------------------------------------------------------------------------
// K1: per-node Q/K projection.  QK[n][c], c = qk*512 + h*64 + g  (bf16)
// (unchanged)
// ---------------------------------------------------------------------------
__global__ __launch_bounds__(256) void qk_project(
    const float* __restrict__ x,
    const float* __restrict__ Wq,
    const float* __restrict__ bq,
    const float* __restrict__ Wk,
    const float* __restrict__ bk,
    unsigned short* __restrict__ qk)
{
    __shared__ float xs[64][65];
    __shared__ float wsb[64][65];

    const int tid = threadIdx.x;
    const int colBase = blockIdx.x * 64;
    const int nodeBase = blockIdx.y * 64;
    const int f = tid & 63;

    for (int n = tid >> 6; n < 64; n += 4) {
        int node = nodeBase + n;
        xs[n][f] = (node < N_NODES) ? x[node * 64 + f] : 0.0f;
    }
    for (int cl = tid >> 6; cl < 64; cl += 4) {
        int c = colBase + cl;
        int hg = c & 511;
        const float* W = (c >> 9) ? Wk : Wq;
        wsb[cl][f] = W[hg * 64 + f];
    }
    __syncthreads();

    const int nb = (tid >> 4) * 4;
    const int cb = (tid & 15) * 4;

    float acc[4][4] = {};
#pragma unroll 8
    for (int k = 0; k < 64; ++k) {
        float a0 = xs[nb + 0][k], a1 = xs[nb + 1][k];
        float a2 = xs[nb + 2][k], a3 = xs[nb + 3][k];
        float b0 = wsb[cb + 0][k], b1 = wsb[cb + 1][k];
        float b2 = wsb[cb + 2][k], b3 = wsb[cb + 3][k];
        acc[0][0] += a0 * b0; acc[0][1] += a0 * b1; acc[0][2] += a0 * b2; acc[0][3] += a0 * b3;
        acc[1][0] += a1 * b0; acc[1][1] += a1 * b1; acc[1][2] += a1 * b2; acc[1][3] += a1 * b3;
        acc[2][0] += a2 * b0; acc[2][1] += a2 * b1; acc[2][2] += a2 * b2; acc[2][3] += a2 * b3;
        acc[3][0] += a3 * b0; acc[3][1] += a3 * b1; acc[3][2] += a3 * b2; acc[3][3] += a3 * b3;
    }

#pragma unroll
    for (int i = 0; i < 4; ++i) {
        int node = nodeBase + nb + i;
        if (node >= N_NODES) continue;
        int c0 = colBase + cb;
        ushort4 sv;
        { int hg = (c0+0)&511; float bias = ((c0+0)>>9) ? bk[hg] : bq[hg]; sv.x = f2bf(acc[i][0]+bias); }
        { int hg = (c0+1)&511; float bias = ((c0+1)>>9) ? bk[hg] : bq[hg]; sv.y = f2bf(acc[i][1]+bias); }
        { int hg = (c0+2)&511; float bias = ((c0+2)>>9) ? bk[hg] : bq[hg]; sv.z = f2bf(acc[i][2]+bias); }
        { int hg = (c0+3)&511; float bias = ((c0+3)>>9) ? bk[hg] : bq[hg]; sv.w = f2bf(acc[i][3]+bias); }
        *reinterpret_cast<ushort4*>(&qk[(size_t)node * COLS + c0]) = sv;
    }
}

// ---------------------------------------------------------------------------
// K2 (MFMA): block = 64 edges, wave = head pair (h0 = 2*wv).
// dk_pre[c=0..127][e=0..15] per tile via 8x mfma_f32_16x16x32_bf16:
//   A = W_dk rows for this head-pair (8 frags, persistent in VGPRs; bias
//       folded at virtual k=20, paired with ef[20]=1.0)
//   B = ef for 16 edges (1 ds_read_b128 from LDS)
// C-frag layout (m89): col = lane&15 = edge, row = 4*(lane>>4)+reg = c
//   -> lane's q/k gather: fixed edge, 4 consecutive f per reg = dwordx2.
// ---------------------------------------------------------------------------
__global__ __launch_bounds__(256, 3) void edge_attn(
    const float* __restrict__ dist,
    const int* __restrict__ nbrs,      // [E][2]
    const float* __restrict__ Wdk,     // [8][64][20]
    const float* __restrict__ bdk,     // [8][64]
    const unsigned short* __restrict__ qk, // [N][1024] bf16
    float* __restrict__ out)           // [E][8]
{
    __shared__ int4 ef_s4[4][64];      // [kgroup][edge] : 8 bf16 each (4 KB)
    __shared__ int2 nbr_s[64];

    const int tid = threadIdx.x;
    const int lane = tid & 63;
    const int wv = tid >> 6;           // head pair
    const int h0 = wv * 2;
    const int l15 = lane & 15;
    const int g = lane >> 4;
    const int e0 = blockIdx.x * 64;

    // ---- persistent A-frags: W_dk for this head pair (+bias at k=20) ----
    short8 aw[8];
#pragma unroll
    for (int m = 0; m < 8; ++m) {
        int R = (h0 + (m >> 2)) * 64 + 16 * (m & 3) + l15;  // row of W_dk
        float w[8];
        if (g < 2) {
            const float* p = Wdk + R * 20 + 8 * g;
            float4 v0 = *reinterpret_cast<const float4*>(p);
            float4 v1 = *reinterpret_cast<const float4*>(p + 4);
            w[0]=v0.x; w[1]=v0.y; w[2]=v0.z; w[3]=v0.w;
            w[4]=v1.x; w[5]=v1.y; w[6]=v1.z; w[7]=v1.w;
        } else if (g == 2) {
            const float* p = Wdk + R * 20 + 16;
            float4 v0 = *reinterpret_cast<const float4*>(p);
            w[0]=v0.x; w[1]=v0.y; w[2]=v0.z; w[3]=v0.w;
            w[4]=bdk[R]; w[5]=0.0f; w[6]=0.0f; w[7]=0.0f;
        } else {
            w[0]=w[1]=w[2]=w[3]=w[4]=w[5]=w[6]=w[7]=0.0f;
        }
        frag_u f;
        f.i.x = f2bf(w[0]) | ((unsigned int)f2bf(w[1]) << 16);
        f.i.y = f2bf(w[2]) | ((unsigned int)f2bf(w[3]) << 16);
        f.i.z = f2bf(w[4]) | ((unsigned int)f2bf(w[5]) << 16);
        f.i.w = f2bf(w[6]) | ((unsigned int)f2bf(w[7]) << 16);
        aw[m] = f.s;
    }

    // ---- phase 1: wave 0 computes ef (bf16) + stashes nbrs ----
    if (tid < 64) {
        int e = e0 + lane;
        bool v = e < N_EDGES;
        float d = v ? dist[e] : 1.0f;
        int2 nn = make_int2(0, 0);
        if (v) nn = *reinterpret_cast<const int2*>(&nbrs[2 * e]);
        nbr_s[lane] = nn;

        float theta = 0.62831853071795864769f * d;   // pi*d/5
        float s1, c1;
        __sincosf(theta, &s1, &c1);
        float env = (d < 5.0f) ? 0.5f * (c1 + 1.0f) : 0.0f;
        float scale = env / d;

        float ef[N_RBF];
        float twoc = 2.0f * c1, sm1 = 0.0f, ss = s1;
#pragma unroll
        for (int r = 0; r < N_RBF; ++r) {
            ef[r] = ss * scale;
            float nx = twoc * ss - sm1;
            sm1 = ss; ss = nx;
        }
        unsigned int w[16];
#pragma unroll
        for (int q = 0; q < 10; ++q)
            w[q] = f2bf(ef[2*q]) | ((unsigned int)f2bf(ef[2*q+1]) << 16);
        w[10] = 0x3F80u;               // k=20 -> 1.0 (bias column), k=21 -> 0
        w[11] = w[12] = w[13] = w[14] = w[15] = 0u;
#pragma unroll
        for (int g2 = 0; g2 < 4; ++g2)
            ef_s4[g2][lane] = make_int4(w[4*g2], w[4*g2+1], w[4*g2+2], w[4*g2+3]);
    }
    __syncthreads();

    const char* qkb = reinterpret_cast<const char*>(qk);

#pragma unroll
    for (int t = 0; t < 4; ++t) {
        // B-frag: ef for 16 edges of this tile
        frag_u bf_;
        bf_.i = ef_s4[g][t * 16 + l15];

        // neighbor ids for this lane's edge
        int2 nn = nbr_s[t * 16 + l15];
        const char* bq = qkb + (size_t)nn.x * 2048 + h0 * 128 + 8 * g;
        const char* bk = qkb + (size_t)nn.y * 2048 + 1024 + h0 * 128 + 8 * g;
        uint2 qv[8], kv[8];
#pragma unroll
        for (int m = 0; m < 8; ++m) {
            qv[m] = *reinterpret_cast<const uint2*>(bq + 32 * m);
            kv[m] = *reinterpret_cast<const uint2*>(bk + 32 * m);
        }

        // dk pre-activation: 8 MFMAs (c-tiles) x K=32 (20 rbf + bias + pad)
        f32x4 acc[8];
#pragma unroll
        for (int m = 0; m < 8; ++m) {
            f32x4 z = {0.0f, 0.0f, 0.0f, 0.0f};
            acc[m] = __builtin_amdgcn_mfma_f32_16x16x32_bf16(aw[m], bf_.s, z, 0, 0, 0);
        }

        // contraction: sum_c q*k*silu(dk_pre) per head
        float tA = 0.0f, tB = 0.0f;
#pragma unroll
        for (int m = 0; m < 8; ++m) {
#pragma unroll
            for (int r2 = 0; r2 < 4; ++r2) {
                unsigned int qw = (r2 < 2) ? qv[m].x : qv[m].y;
                unsigned int kw = (r2 < 2) ? kv[m].x : kv[m].y;
                float qf = (r2 & 1) ? __uint_as_float(qw & 0xFFFF0000u)
                                    : __uint_as_float(qw << 16);
                float kf = (r2 & 1) ? __uint_as_float(kw & 0xFFFF0000u)
                                    : __uint_as_float(kw << 16);
                float dk = fsilu(acc[m][r2]);
                float p = qf * kf;
                if (m < 4) tA = fmaf(p, dk, tA);
                else       tB = fmaf(p, dk, tB);
            }
        }

        // reduce across the 4 lanes sharing this edge (l15 class)
        tA += __shfl_xor(tA, 16);
        tA += __shfl_xor(tA, 32);
        tB += __shfl_xor(tB, 16);
        tB += __shfl_xor(tB, 32);

        int e = e0 + t * 16 + l15;
        if (lane < 16 && e < N_EDGES) {
            float2 o = make_float2(fsilu(tA), fsilu(tB));
            *reinterpret_cast<float2*>(out + (size_t)e * 8 + h0) = o;
        }
    }
}

extern "C" void kernel_launch(void* const* d_in, const int* in_sizes, int n_in,
                              void* d_out, int out_size, void* d_ws, size_t ws_size,
                              hipStream_t stream) {
    const float* dist = (const float*)d_in[0];
    const int* nbrs   = (const int*)d_in[1];
    const float* x_i  = (const float*)d_in[2];
    const float* W_q  = (const float*)d_in[3];
    const float* b_q  = (const float*)d_in[4];
    const float* W_k  = (const float*)d_in[5];
    const float* b_k  = (const float*)d_in[6];
    const float* W_dk = (const float*)d_in[7];
    const float* b_dk = (const float*)d_in[8];
    float* out = (float*)d_out;

    unsigned short* qkbuf = (unsigned short*)d_ws;  // 20000*1024 bf16 = 41 MB

    dim3 g1(COLS / 64, (N_NODES + 63) / 64);
    qk_project<<<g1, 256, 0, stream>>>(x_i, W_q, b_q, W_k, b_k, qkbuf);

    const int nb = (N_EDGES + 63) / 64;   // 2344 blocks, 64 edges each
    edge_attn<<<nb, 256, 0, stream>>>(dist, nbrs, W_dk, b_dk, qkbuf, out);
}